// Round 12
// baseline (7662.572 us; speedup 1.0000x reference)
//
#include <hip/hip_runtime.h>

typedef unsigned short u16;
typedef unsigned int u32;
typedef _Float16 f16;
typedef f16 h2 __attribute__((ext_vector_type(2)));
typedef f16 h4 __attribute__((ext_vector_type(4)));
typedef f16 h8 __attribute__((ext_vector_type(8)));
typedef u16 u16x8 __attribute__((ext_vector_type(8)));
typedef float f32x4 __attribute__((ext_vector_type(4)));

#define B_ 64
#define F_ 128
#define H_ 512
#define S_ 512
#define T_ 96
#define NB 256
#define NT 1024

// ---- workspace byte offsets (audited chain, all disjoint) ----
#define FLAG_OFF  0ul          // u32[256] @64B stride           -> 16384
#define DEN_OFF   20480ul      // f32 [64][4]                    -> 21504
#define CQ_OFF    24576ul      // u32 [64][4][256] f16x2 c parts -> 286720
#define HNEW_OFF  327680ul     // f32 [2][64][512]               -> 589824
#define WTS_OFF   589824ul     // f16 [2359296]                  -> 5308416
#define ENCP_OFF  8388608ul    // f16 [64][512][512] 2*(enc@Wa2^T+ba) -> 41943040
#define ENCF_OFF  41943040ul   // f16 [64][512][512] enc         -> 75497472

// f16-element offsets inside WTS
#define WA1_E  0        // [512][512]
#define WA2_E  262144   // [512][512]
#define WHH_E  524288   // [1536][512]
#define WC_E   1310720  // [1536][512]
#define WX_E   2097152  // [1536][128]
#define WOUT_E 2293760  // [128][512]
#define WTS_N  2359296

__device__ __forceinline__ float fdot2(h2 a, h2 b, float c) {
#if __has_builtin(__builtin_amdgcn_fdot2)
  return __builtin_amdgcn_fdot2(a, b, c, false);
#else
  return c + (float)a[0] * (float)b[0] + (float)a[1] * (float)b[1];
#endif
}
__device__ __forceinline__ u32 packh2(float a, float b) {
  h2 p; p[0] = (f16)a; p[1] = (f16)b;
  return __builtin_bit_cast(u32, p);
}
__device__ __forceinline__ h2 unpackh2(u32 v) { return __builtin_bit_cast(h2, v); }
__device__ __forceinline__ void xstf(float* p, float v) {
  __hip_atomic_exchange(p, v, __ATOMIC_RELAXED, __HIP_MEMORY_SCOPE_AGENT);
}
__device__ __forceinline__ void xstu(u32* p, u32 v) {
  __hip_atomic_exchange(p, v, __ATOMIC_RELAXED, __HIP_MEMORY_SCOPE_AGENT);
}
__device__ __forceinline__ float aldf(const float* p) {
  return __hip_atomic_load(p, __ATOMIC_RELAXED, __HIP_MEMORY_SCOPE_AGENT);
}
__device__ __forceinline__ u32 aldu(const u32* p) {
  return __hip_atomic_load(p, __ATOMIC_RELAXED, __HIP_MEMORY_SCOPE_AGENT);
}

// 4-block group barrier. tid0 stores my flag FIRST (program order within wave
// 0), then lanes 0..3 (minus self) poll peer flags. Store always issues before
// any spin -> deadlock-free; bounded spin -> visible failure, never a hang.
__device__ __forceinline__ void groupbar(u32* flags, int bid, int q, unsigned ep) {
  __builtin_amdgcn_s_waitcnt(0);   // every wave drains its own data stores
  __syncthreads();
  const int tid = threadIdx.x;
  if (tid == 0)
    __hip_atomic_exchange(flags + bid * 16, ep, __ATOMIC_RELAXED, __HIP_MEMORY_SCOPE_AGENT);
  if (tid < 4 && tid != q) {
    u32* pf = flags + (bid - q + tid) * 16;
    int guard = 0;
    while (__hip_atomic_load(pf, __ATOMIC_RELAXED, __HIP_MEMORY_SCOPE_AGENT) < ep) {
      __builtin_amdgcn_s_sleep(1);
      if (++guard > (1 << 17)) break;
    }
  }
  __syncthreads();
  asm volatile("" ::: "memory");
}

// ---------------- enc f32 -> f16 linear (one-time) ----------------
__global__ __launch_bounds__(256) void transcode_enc(const float* __restrict__ enc,
                                                     f16* __restrict__ out) {
  int i = blockIdx.x * 256 + threadIdx.x;
  #pragma unroll
  for (int u = 0; u < 4; ++u) {
    int idx = i + u * 1048576;
    float4 v = ((const float4*)enc)[idx];
    h4 o = {(f16)v.x, (f16)v.y, (f16)v.z, (f16)v.w};
    ((h4*)out)[idx] = o;
  }
}

// ---------------- pack all weights to f16 (one-time) ----------------
__global__ __launch_bounds__(256) void pack_weights(
    const float* __restrict__ Wa, const float* __restrict__ Whh,
    const float* __restrict__ Wih, const float* __restrict__ Wout,
    f16* __restrict__ WTS) {
  int i = blockIdx.x * 256 + threadIdx.x;
  if (i >= WTS_N) return;
  float x;
  if (i < WA2_E) {
    int n = i >> 9, k = i & 511;
    x = Wa[(size_t)n * 1024 + k];
  } else if (i < WHH_E) {
    int j = i - WA2_E; int n = j >> 9, k = j & 511;
    x = Wa[(size_t)n * 1024 + 512 + k];
  } else if (i < WC_E) {
    int j = i - WHH_E; int n = j >> 9, k = j & 511;
    x = Whh[(size_t)n * 512 + k];
  } else if (i < WX_E) {
    int j = i - WC_E; int n = j >> 9, k = j & 511;
    x = Wih[(size_t)n * 640 + 128 + k];
  } else if (i < WOUT_E) {
    int j = i - WX_E; int n = j >> 7, k = j & 127;
    x = Wih[(size_t)n * 640 + k];
  } else {
    int j = i - WOUT_E; int n = j >> 9, k = j & 511;
    x = Wout[(size_t)n * 512 + k];
  }
  WTS[i] = (f16)x;
}

// ------- MFMA: ENCP[m][n] = 2*(sum_k ENCF[m][k]*WA2[n][k] + ba[n]), f16 -------
__global__ __launch_bounds__(256) void mfma_encproj(const u16* __restrict__ Abf,
                                                    const u16* __restrict__ Bbf,
                                                    const float* __restrict__ ba,
                                                    f16* __restrict__ C) {
  __shared__ u16 As[128 * 40];
  __shared__ u16 Bs[128 * 40];
  const int tid = threadIdx.x, lane = tid & 63, w = tid >> 6;
  const int m0 = blockIdx.x << 7, n0 = blockIdx.y << 7;
  const int r0 = lane & 15, kh = lane >> 4;
  f32x4 acc[2][8] = {};
  for (int k0 = 0; k0 < 512; k0 += 32) {
    #pragma unroll
    for (int i = 0; i < 2; ++i) {
      int e = tid + (i << 8);
      int row = e >> 2, g = e & 3;
      *(u16x8*)&As[row * 40 + (g << 3)] =
          *(const u16x8*)(Abf + (size_t)(m0 + row) * 512 + k0 + (g << 3));
      *(u16x8*)&Bs[row * 40 + (g << 3)] =
          *(const u16x8*)(Bbf + (size_t)(n0 + row) * 512 + k0 + (g << 3));
    }
    __syncthreads();
    h8 a[2], bb[8];
    #pragma unroll
    for (int r = 0; r < 2; ++r)
      a[r] = *(const h8*)&As[((w << 5) + (r << 4) + r0) * 40 + (kh << 3)];
    #pragma unroll
    for (int c = 0; c < 8; ++c)
      bb[c] = *(const h8*)&Bs[((c << 4) + r0) * 40 + (kh << 3)];
    #pragma unroll
    for (int r = 0; r < 2; ++r)
      #pragma unroll
      for (int c = 0; c < 8; ++c)
        acc[r][c] = __builtin_amdgcn_mfma_f32_16x16x32_f16(a[r], bb[c], acc[r][c], 0, 0, 0);
    __syncthreads();
  }
  #pragma unroll
  for (int c = 0; c < 8; ++c) {
    int n = n0 + (c << 4) + r0;
    float bav = ba[n];
    #pragma unroll
    for (int r = 0; r < 2; ++r) {
      int mbase = m0 + (w << 5) + (r << 4) + (kh << 2);
      #pragma unroll
      for (int t = 0; t < 4; ++t)
        C[(size_t)(mbase + t) * 512 + n] = (f16)(2.f * (acc[r][c][t] + bav));
    }
  }
}

struct Params {
  const float *hidden, *dec_input, *Wv, *bih, *bhh, *bout;
  const f16 *ENCP, *ENCF, *WA1, *WHH, *WC, *WX, *WOUT;
  u32 *CQ, *flags;
  float *DEN, *HNEW, *out;
};

__global__ __launch_bounds__(NT, 1) void decoder4(Params p) {
  // flat LDS (~43 KB)
  __shared__ __align__(16) h2 hh2[256];
  __shared__ __align__(16) h2 xh2[64];
  __shared__ __align__(16) h2 ch2[256];
  __shared__ float hfL[128];
  __shared__ __align__(16) float hpL[512];
  __shared__ float g1L[384], g2L[384], gcL[384];
  __shared__ float cpart[16][8][65];
  __shared__ float dWL[16], dtmp[4], invL[1];

  const int bid = blockIdx.x, tid = threadIdx.x;
  const int lane = tid & 63, w = tid >> 6;
  const int b = bid >> 2, q = bid & 3;     // group = 4 blocks of one batch
  unsigned ep = 0;

  float wv2[8], wvs = 0.f;
  {
    const float* wp = p.Wv + lane * 8;
    #pragma unroll
    for (int e = 0; e < 8; ++e) { float v = wp[e]; wv2[e] = -2.f * v; wvs += v; }
  }

  for (int t = 0; t < T_; ++t) {
    float* HNc = p.HNEW + (t & 1) * 32768;
    float* HNn = p.HNEW + ((t + 1) & 1) * 32768;

    // ---- A1: load full h (and x at t==0) ----
    if (tid < 512) {
      float v = (t == 0) ? p.hidden[(size_t)b * 512 + tid]
                         : aldf(HNc + (size_t)b * 512 + tid);
      float vp = __shfl_xor(v, 1);
      if (!(tid & 1)) hh2[tid >> 1] = h2{(f16)v, (f16)vp};
      unsigned d = (unsigned)(tid - (q << 7));
      if (d < 128u) hfL[d] = v;
    } else if (t == 0 && tid < 640) {
      int n = tid - 512;
      float v = p.dec_input[(size_t)b * 128 + n];
      float vp = __shfl_down(v, 1);
      if (!(n & 1)) xh2[n >> 1] = h2{(f16)v, (f16)vp};
    }
    __syncthreads();

    // ---- A2: 1024 K=512 rows: hp(512) | gh(384) | out/x(128) ----
    {
      const f16* wr;
      if (tid < 512) {
        wr = p.WA1 + ((size_t)tid << 9);
      } else if (tid < 896) {
        int idx = tid - 512;
        int jg = ((idx >> 7) << 9) + (q << 7) + (idx & 127);
        wr = p.WHH + ((size_t)jg << 9);
      } else {
        wr = p.WOUT + ((size_t)(tid - 896) << 9);
      }
      float acc = 0.f;
      if (tid < 896 || t > 0) {
        #pragma unroll 8
        for (int k4 = 0; k4 < 64; ++k4) {
          h8 hv = *(const h8*)&hh2[k4 * 4];
          h8 wv = *(const h8*)(wr + k4 * 8);
          const h2 *hq = (const h2*)&hv, *wq = (const h2*)&wv;
          #pragma unroll
          for (int e = 0; e < 4; ++e) acc = fdot2(hq[e], wq[e], acc);
        }
      }
      if (tid < 512) {
        hpL[tid] = 2.f * acc;
      } else if (tid < 896) {
        int idx = tid - 512;
        int jg = ((idx >> 7) << 9) + (q << 7) + (idx & 127);
        g2L[idx] = acc + p.bhh[jg];
      } else if (t > 0) {
        int n = tid - 896;
        float val = acc + p.bout[n];
        float vp = __shfl_down(val, 1);
        if (q == 0) p.out[((size_t)b * T_ + (t - 1)) * F_ + n] = val;
        if (!(n & 1)) xh2[n >> 1] = h2{(f16)val, (f16)vp};
      }
    }
    __syncthreads();

    // ---- A3: gx (threads 0..383) + scores/c-partials over s-quarter ----
    if (tid < 384) {
      int jg = ((tid >> 7) << 9) + (q << 7) + (tid & 127);
      const f16* wx = p.WX + ((size_t)jg << 7);
      float acc = 0.f;
      #pragma unroll
      for (int k4 = 0; k4 < 16; ++k4) {
        h8 xv = *(const h8*)&xh2[k4 * 4];
        h8 wv = *(const h8*)(wx + k4 * 8);
        const h2 *xq = (const h2*)&xv, *wq = (const h2*)&wv;
        #pragma unroll
        for (int e = 0; e < 4; ++e) acc = fdot2(xq[e], wq[e], acc);
      }
      g1L[tid] = acc + p.bih[jg];
    }
    {
      float hp8[8];
      *(float4*)hp8 = *(const float4*)&hpL[lane * 8];
      *(float4*)(hp8 + 4) = *(const float4*)&hpL[lane * 8 + 4];
      const size_t sbase = (size_t)b * 512 + (q << 7) + w * 8;
      const f16* pb = p.ENCP + (sbase << 9) + lane * 8;
      const f16* eb = p.ENCF + (sbase << 9) + lane * 8;
      float c8[8] = {};
      float den = 0.f;
      #pragma unroll
      for (int i = 0; i < 8; ++i) {
        h8 pv = *(const h8*)(pb + ((size_t)i << 9));
        float acc = wvs;
        #pragma unroll
        for (int e = 0; e < 8; ++e) {
          float e2 = __expf(hp8[e] + (float)pv[e]);     // e^{2x}
          acc += wv2[e] * __builtin_amdgcn_rcpf(e2 + 1.f);
        }
        #pragma unroll
        for (int off = 32; off; off >>= 1) acc += __shfl_xor(acc, off);
        float es = __expf(acc);   // |score| <= ~11: un-normalized exp safe
        den += es;
        h8 ev = *(const h8*)(eb + ((size_t)i << 9));
        #pragma unroll
        for (int e = 0; e < 8; ++e) c8[e] += es * (float)ev[e];
      }
      #pragma unroll
      for (int e = 0; e < 8; ++e) cpart[w][e][lane] = c8[e];
      if (lane == 0) dWL[w] = den;
      __syncthreads();
      if (tid < 256) {
        int h0 = 2 * tid, h1 = 2 * tid + 1;
        float v0 = 0.f, v1 = 0.f;
        #pragma unroll
        for (int ww = 0; ww < 16; ++ww) {
          v0 += cpart[ww][h0 & 7][h0 >> 3];
          v1 += cpart[ww][h1 & 7][h1 >> 3];
        }
        xstu(p.CQ + (((b << 2) | q) << 8) + tid,
             packh2(v0 * 1.220703125e-4f, v1 * 1.220703125e-4f));   // x 2^-13
      } else if (tid == 256) {
        float d = 0.f;
        #pragma unroll
        for (int i = 0; i < 16; ++i) d += dWL[i];
        xstf(p.DEN + (b << 2) + q, d);
      }
    }
    groupbar(p.flags, bid, q, ++ep);

    // ---- B: c assembly + gc + GRU update (h-quarter q) ----
    if (tid < 4) dtmp[tid] = aldf(p.DEN + (b << 2) + tid);
    __syncthreads();
    if (tid == 0)
      invL[0] = 8192.f * __builtin_amdgcn_rcpf(dtmp[0] + dtmp[1] + dtmp[2] + dtmp[3]);
    __syncthreads();
    if (tid < 256) {
      float lo = 0.f, hi = 0.f;
      #pragma unroll
      for (int sq = 0; sq < 4; ++sq) {
        h2 v = unpackh2(aldu(p.CQ + (((b << 2) | sq) << 8) + tid));
        lo += (float)v[0]; hi += (float)v[1];
      }
      float inv = invL[0];
      ch2[tid] = h2{(f16)(lo * inv), (f16)(hi * inv)};
    }
    __syncthreads();
    if (tid < 384) {
      int jg = ((tid >> 7) << 9) + (q << 7) + (tid & 127);
      const f16* wc = p.WC + ((size_t)jg << 9);
      float acc = 0.f;
      #pragma unroll 4
      for (int k4 = 0; k4 < 64; ++k4) {
        h8 cv = *(const h8*)&ch2[k4 * 4];
        h8 wv = *(const h8*)(wc + k4 * 8);
        const h2 *cq = (const h2*)&cv, *wq = (const h2*)&wv;
        #pragma unroll
        for (int e = 0; e < 4; ++e) acc = fdot2(cq[e], wq[e], acc);
      }
      gcL[tid] = acc;
    }
    __syncthreads();
    if (tid < 128) {
      float rpre = g1L[tid] + gcL[tid] + g2L[tid];
      float zpre = g1L[128 + tid] + gcL[128 + tid] + g2L[128 + tid];
      float rr = __builtin_amdgcn_rcpf(1.f + __expf(-rpre));
      float zz = __builtin_amdgcn_rcpf(1.f + __expf(-zpre));
      float narg = g1L[256 + tid] + gcL[256 + tid] + rr * g2L[256 + tid];
      float nn = 1.f - 2.f * __builtin_amdgcn_rcpf(1.f + __expf(2.f * narg));
      float hn = (1.f - zz) * nn + zz * hfL[tid];
      xstf(HNn + (size_t)b * 512 + (q << 7) + tid, hn);
    }
    groupbar(p.flags, bid, q, ++ep);
  }

  // ---- epilogue: out[:, T-1, :] (q==0 blocks; final h in HNEW parity 0) ----
  if (q == 0) {
    if (tid < 512) {
      float v = aldf(p.HNEW + (size_t)b * 512 + tid);
      float vp = __shfl_xor(v, 1);
      if (!(tid & 1)) hh2[tid >> 1] = h2{(f16)v, (f16)vp};
    }
    __syncthreads();
    if (tid >= 896) {
      int n = tid - 896;
      const f16* wr = p.WOUT + ((size_t)n << 9);
      float acc = 0.f;
      #pragma unroll 8
      for (int k4 = 0; k4 < 64; ++k4) {
        h8 hv = *(const h8*)&hh2[k4 * 4];
        h8 wv = *(const h8*)(wr + k4 * 8);
        const h2 *hq = (const h2*)&hv, *wq = (const h2*)&wv;
        #pragma unroll
        for (int e = 0; e < 4; ++e) acc = fdot2(hq[e], wq[e], acc);
      }
      p.out[((size_t)b * T_ + (T_ - 1)) * F_ + n] = acc + p.bout[n];
    }
  }
}

extern "C" void kernel_launch(void* const* d_in, const int* in_sizes, int n_in,
                              void* d_out, int out_size, void* d_ws, size_t ws_size,
                              hipStream_t stream) {
  const float* dec_input = (const float*)d_in[0];
  const float* hidden    = (const float*)d_in[1];
  const float* enc       = (const float*)d_in[2];
  // d_in[3] expected_outputs, d_in[4] dec_output_len (fixed 96) unused
  const float* Wa   = (const float*)d_in[5];
  const float* ba   = (const float*)d_in[6];
  const float* Wv   = (const float*)d_in[7];
  // d_in[8] bv cancels in softmax
  const float* Wih  = (const float*)d_in[9];
  const float* bih  = (const float*)d_in[10];
  const float* Whh  = (const float*)d_in[11];
  const float* bhh  = (const float*)d_in[12];
  const float* Wout = (const float*)d_in[13];
  const float* bout = (const float*)d_in[14];

  char* ws = (char*)d_ws;
  f16* WTS  = (f16*)(ws + WTS_OFF);
  f16* ENCP = (f16*)(ws + ENCP_OFF);
  f16* ENCF = (f16*)(ws + ENCF_OFF);

  Params p;
  p.hidden = hidden; p.dec_input = dec_input; p.Wv = Wv;
  p.bih = bih; p.bhh = bhh; p.bout = bout;
  p.ENCP = ENCP; p.ENCF = ENCF;
  p.WA1 = WTS + WA1_E; p.WHH = WTS + WHH_E; p.WC = WTS + WC_E;
  p.WX = WTS + WX_E; p.WOUT = WTS + WOUT_E;
  p.CQ = (u32*)(ws + CQ_OFF);
  p.flags = (u32*)(ws + FLAG_OFF);
  p.DEN = (float*)(ws + DEN_OFF);
  p.HNEW = (float*)(ws + HNEW_OFF);
  p.out = (float*)d_out;

  hipMemsetAsync(ws, 0, 20480, stream);   // flag lines
  hipLaunchKernelGGL(transcode_enc, dim3(4096), dim3(256), 0, stream, enc, ENCF);
  hipLaunchKernelGGL(pack_weights, dim3(9216), dim3(256), 0, stream,
                     Wa, Whh, Wih, Wout, WTS);
  hipLaunchKernelGGL(mfma_encproj, dim3(256, 4), dim3(256), 0, stream,
                     (const u16*)ENCF, (const u16*)(WTS + WA2_E), ba, ENCP);

  void* args[] = {&p};
  hipLaunchCooperativeKernel((void*)decoder4, dim3(NB), dim3(NT), args, 0,
                             stream);
}

// Round 13
// 3715.421 us; speedup vs baseline: 2.0624x; 2.0624x over previous
//
#include <hip/hip_runtime.h>

typedef unsigned short u16;
typedef unsigned int u32;
typedef _Float16 f16;
typedef f16 h2 __attribute__((ext_vector_type(2)));
typedef f16 h4 __attribute__((ext_vector_type(4)));
typedef f16 h8 __attribute__((ext_vector_type(8)));
typedef u16 u16x8 __attribute__((ext_vector_type(8)));
typedef float f32x4 __attribute__((ext_vector_type(4)));

#define B_ 64
#define F_ 128
#define H_ 512
#define S_ 512
#define T_ 96
#define NB 256
#define NT 1024

// ---- workspace byte offsets (r8 layout, audited disjoint) ----
#define FLAG_OFF  0ul          // u32[256] @64B stride (16384 B)
#define GEN_OFF   16384ul      // u32[8] @64B stride
#define HP_OFF    20480ul      // f32 [64][512]
#define XF_OFF    151552ul     // f32 [64][128]
#define DEN_OFF   184320ul     // f32 [64][4]
#define CQ_OFF    185344ul     // u32 [64][4][256]  (f16x2 packed c partials, x 2^-13)
#define HNEW_OFF  447488ul     // f32 [2][64][512]
#define WTS_OFF   709632ul     // f16 [2359296]
#define ENCP_OFF  5428224ul    // f16 [64][512][512]  2*(enc@Wa2^T + ba)
#define ENCF_OFF  38982656ul   // f16 [64][512][512]  enc
// end: 72537088 (~69.2 MiB)

// f16-element offsets inside WTS
#define WA1_E  0        // [512][512]  Wa[:, :512]
#define WA2_E  262144   // [512][512]  Wa[:, 512:]
#define WHH_E  524288   // [1536][512]
#define WC_E   1310720  // [1536][512]  Wih[:, 128:]
#define WX_E   2097152  // [1536][128]  Wih[:, :128]
#define WOUT_E 2293760  // [128][512]
#define WTS_N  2359296

__device__ __forceinline__ float fdot2(h2 a, h2 b, float c) {
#if __has_builtin(__builtin_amdgcn_fdot2)
  return __builtin_amdgcn_fdot2(a, b, c, false);
#else
  return c + (float)a[0] * (float)b[0] + (float)a[1] * (float)b[1];
#endif
}
__device__ __forceinline__ u32 packh2(float a, float b) {
  h2 p; p[0] = (f16)a; p[1] = (f16)b;
  return __builtin_bit_cast(u32, p);
}
__device__ __forceinline__ h2 unpackh2(u32 v) { return __builtin_bit_cast(h2, v); }
__device__ __forceinline__ void xstf(float* p, float v) {
  __hip_atomic_exchange(p, v, __ATOMIC_RELAXED, __HIP_MEMORY_SCOPE_AGENT);
}
__device__ __forceinline__ void xstu(u32* p, u32 v) {
  __hip_atomic_exchange(p, v, __ATOMIC_RELAXED, __HIP_MEMORY_SCOPE_AGENT);
}
__device__ __forceinline__ float aldf(const float* p) {
  return __hip_atomic_load(p, __ATOMIC_RELAXED, __HIP_MEMORY_SCOPE_AGENT);
}
__device__ __forceinline__ u32 aldu(const u32* p) {
  return __hip_atomic_load(p, __ATOMIC_RELAXED, __HIP_MEMORY_SCOPE_AGENT);
}

// Fence-free grid barrier — r8-proven version verbatim.
__device__ __forceinline__ void gridbar(u32* flags, u32* gen, unsigned ep) {
  __builtin_amdgcn_s_waitcnt(0);   // drain our exchange-RMWs (acked at MALL)
  __syncthreads();
  const int bid = blockIdx.x, tid = threadIdx.x;
  if (bid == 0) {
    if (tid >= 64 && tid < 319) {  // 255 pollers for blocks 1..255
      u32* pf = flags + (tid - 63) * 16;
      int guard = 0;
      while (__hip_atomic_load(pf, __ATOMIC_RELAXED, __HIP_MEMORY_SCOPE_AGENT) < ep) {
        __builtin_amdgcn_s_sleep(1);
        if (++guard > (1 << 16)) break;
      }
    }
    __syncthreads();
    if (tid < 8)
      __hip_atomic_exchange(gen + tid * 16, ep, __ATOMIC_RELAXED, __HIP_MEMORY_SCOPE_AGENT);
  } else {
    if (tid == 0) {
      __hip_atomic_exchange(flags + bid * 16, ep, __ATOMIC_RELAXED, __HIP_MEMORY_SCOPE_AGENT);
      u32* pg = gen + (bid & 7) * 16;
      int guard = 0;
      while (__hip_atomic_load(pg, __ATOMIC_RELAXED, __HIP_MEMORY_SCOPE_AGENT) < ep) {
        __builtin_amdgcn_s_sleep(1);
        if (++guard > (1 << 17)) break;
      }
    }
  }
  __syncthreads();
  asm volatile("" ::: "memory");
}

// ---------------- enc f32 -> f16 linear (one-time) ----------------
__global__ __launch_bounds__(256) void transcode_enc(const float* __restrict__ enc,
                                                     f16* __restrict__ out) {
  int i = blockIdx.x * 256 + threadIdx.x;
  #pragma unroll
  for (int u = 0; u < 4; ++u) {
    int idx = i + u * 1048576;
    float4 v = ((const float4*)enc)[idx];
    h4 o = {(f16)v.x, (f16)v.y, (f16)v.z, (f16)v.w};
    ((h4*)out)[idx] = o;
  }
}

// ---------------- pack all weights to f16 (one-time) ----------------
__global__ __launch_bounds__(256) void pack_weights(
    const float* __restrict__ Wa, const float* __restrict__ Whh,
    const float* __restrict__ Wih, const float* __restrict__ Wout,
    f16* __restrict__ WTS) {
  int i = blockIdx.x * 256 + threadIdx.x;
  if (i >= WTS_N) return;
  float x;
  if (i < WA2_E) {                       // Wa1
    int n = i >> 9, k = i & 511;
    x = Wa[(size_t)n * 1024 + k];
  } else if (i < WHH_E) {                // Wa2
    int j = i - WA2_E; int n = j >> 9, k = j & 511;
    x = Wa[(size_t)n * 1024 + 512 + k];
  } else if (i < WC_E) {                 // Whh
    int j = i - WHH_E; int n = j >> 9, k = j & 511;
    x = Whh[(size_t)n * 512 + k];
  } else if (i < WX_E) {                 // Wih c-part
    int j = i - WC_E; int n = j >> 9, k = j & 511;
    x = Wih[(size_t)n * 640 + 128 + k];
  } else if (i < WOUT_E) {               // Wih x-part
    int j = i - WX_E; int n = j >> 7, k = j & 127;
    x = Wih[(size_t)n * 640 + k];
  } else {                               // Wout
    int j = i - WOUT_E; int n = j >> 9, k = j & 511;
    x = Wout[(size_t)n * 512 + k];
  }
  WTS[i] = (f16)x;
}

// ------- MFMA: ENCP[m][n] = 2*(sum_k ENCF[m][k]*WA2[n][k] + ba[n]), f16, linear -------
__global__ __launch_bounds__(256) void mfma_encproj(const u16* __restrict__ Abf,
                                                    const u16* __restrict__ Bbf,
                                                    const float* __restrict__ ba,
                                                    f16* __restrict__ C) {
  __shared__ u16 As[128 * 40];
  __shared__ u16 Bs[128 * 40];
  const int tid = threadIdx.x, lane = tid & 63, w = tid >> 6;
  const int m0 = blockIdx.x << 7, n0 = blockIdx.y << 7;
  const int r0 = lane & 15, kh = lane >> 4;
  f32x4 acc[2][8] = {};
  for (int k0 = 0; k0 < 512; k0 += 32) {
    #pragma unroll
    for (int i = 0; i < 2; ++i) {
      int e = tid + (i << 8);
      int row = e >> 2, g = e & 3;
      *(u16x8*)&As[row * 40 + (g << 3)] =
          *(const u16x8*)(Abf + (size_t)(m0 + row) * 512 + k0 + (g << 3));
      *(u16x8*)&Bs[row * 40 + (g << 3)] =
          *(const u16x8*)(Bbf + (size_t)(n0 + row) * 512 + k0 + (g << 3));
    }
    __syncthreads();
    h8 a[2], bb[8];
    #pragma unroll
    for (int r = 0; r < 2; ++r)
      a[r] = *(const h8*)&As[((w << 5) + (r << 4) + r0) * 40 + (kh << 3)];
    #pragma unroll
    for (int c = 0; c < 8; ++c)
      bb[c] = *(const h8*)&Bs[((c << 4) + r0) * 40 + (kh << 3)];
    #pragma unroll
    for (int r = 0; r < 2; ++r)
      #pragma unroll
      for (int c = 0; c < 8; ++c)
        acc[r][c] = __builtin_amdgcn_mfma_f32_16x16x32_f16(a[r], bb[c], acc[r][c], 0, 0, 0);
    __syncthreads();
  }
  #pragma unroll
  for (int c = 0; c < 8; ++c) {
    int n = n0 + (c << 4) + r0;
    float bav = ba[n];
    #pragma unroll
    for (int r = 0; r < 2; ++r) {
      int mbase = m0 + (w << 5) + (r << 4) + (kh << 2);
      #pragma unroll
      for (int t = 0; t < 4; ++t)
        C[(size_t)(mbase + t) * 512 + n] = (f16)(2.f * (acc[r][c][t] + bav));
    }
  }
}

struct Params {
  const float *hidden, *dec_input, *Wv, *bih, *bhh, *bout;
  const f16 *ENCP, *ENCF, *WA1, *WHH, *WC, *WX, *WOUT;
  float *HP, *XF, *DEN, *HNEW;
  u32 *CQ, *flags, *gen;
  float *out;
};

__global__ __launch_bounds__(NT, 1) void decoder_phases(Params p) {
  __shared__ __align__(16) float hpL[512];
  __shared__ float cpart[16][8][65];   // r13 edit: per-wave c-partials, conflict-free
  __shared__ float dWL[16];
  __shared__ __align__(16) h2 ch2L[4][256];
  __shared__ __align__(16) h2 hh2L[4][256];
  __shared__ __align__(16) h2 xh2L[4][64];
  __shared__ float hfL[4][32];
  __shared__ float invL[4];
  __shared__ float g1L[384], g2L[384];

  const int bid = blockIdx.x, tid = threadIdx.x;
  const int lane = tid & 63, w = tid >> 6;
  unsigned ep = 0;

  // phase-role constants
  const int ab = bid >> 2, asq = bid & 3;          // A: (batch, s-quarter)
  const int bg = bid >> 4;                         // B/C: 4-batch group
  const int rs = bid & 15;                         // B: h-slice; C: row-slice
  const int hsb = rs * 32;

  float wv2[8]; float wvs = 0.f;
  {
    const float* wp = p.Wv + lane * 8;
    #pragma unroll
    for (int e = 0; e < 8; ++e) { float v = wp[e]; wv2[e] = -2.f * v; wvs += v; }
  }

  // ================= init =================
  #pragma unroll
  for (int rep = 0; rep < 2; ++rep) {
    int idx = rep * NT + tid;
    int b4 = idx >> 9, i = idx & 511;
    float v = p.hidden[(size_t)(bg * 4 + b4) * 512 + i];
    float vp = __shfl_xor(v, 1);
    if (!(i & 1)) hh2L[b4][i >> 1] = h2{(f16)v, (f16)vp};
  }
  if (rs == 0) {
    #pragma unroll
    for (int rep = 0; rep < 2; ++rep) {
      int idx = rep * NT + tid;
      int b4 = idx >> 9, i = idx & 511;
      xstf(p.HNEW + (size_t)(bg * 4 + b4) * 512 + i,
           p.hidden[(size_t)(bg * 4 + b4) * 512 + i]);
    }
  } else if (rs == 1) {
    if (tid < 512) {
      int b = bg * 4 + (tid >> 7), n = tid & 127;
      xstf(p.XF + b * 128 + n, p.dec_input[b * 128 + n]);
    }
  }
  __syncthreads();
  if (tid < 160) {
    int row = rs * 40 + (tid >> 2), b4 = tid & 3;
    if (row < 512) {
      const f16* wr = p.WA1 + (size_t)row * 512;
      float acc = 0.f;
      #pragma unroll 8
      for (int k4 = 0; k4 < 64; ++k4) {
        h8 hv = *(const h8*)&hh2L[b4][k4 * 4];
        h8 wv = *(const h8*)(wr + k4 * 8);
        const h2 *hq = (const h2*)&hv, *wq = (const h2*)&wv;
        #pragma unroll
        for (int e = 0; e < 4; ++e) acc = fdot2(hq[e], wq[e], acc);
      }
      xstf(p.HP + (size_t)(bg * 4 + b4) * 512 + row, 2.f * acc);
    }
  }
  gridbar(p.flags, p.gen, ++ep);

  for (int step = 0; step < T_; ++step) {
    const int cur = step & 1, nxt = cur ^ 1;
    float* HNc = p.HNEW + cur * (64 * 512);
    float* HNn = p.HNEW + nxt * (64 * 512);

    // ================= A: scores + exp + c-partials over s-quarter =================
    if (tid < 512) {
      hpL[tid] = aldf(p.HP + (size_t)ab * 512 + tid);
    }
    __syncthreads();
    {
      float hp8[8];
      *(float4*)hp8 = *(const float4*)&hpL[lane * 8];
      *(float4*)(hp8 + 4) = *(const float4*)&hpL[lane * 8 + 4];
      const size_t sbase = (size_t)ab * 512 + asq * 128 + w * 8;
      const f16* pb = p.ENCP + (sbase << 9) + lane * 8;
      const f16* eb = p.ENCF + (sbase << 9) + lane * 8;
      float c8[8] = {};
      float den = 0.f;
      #pragma unroll
      for (int i = 0; i < 8; ++i) {
        h8 pv = *(const h8*)(pb + ((size_t)i << 9));
        float acc = wvs;
        #pragma unroll
        for (int e = 0; e < 8; ++e) {
          float e2 = __expf(hp8[e] + (float)pv[e]);     // e^{2x}
          acc += wv2[e] * __builtin_amdgcn_rcpf(e2 + 1.f);  // wv*(1 - 2/(1+e^2x))
        }
        #pragma unroll
        for (int off = 32; off; off >>= 1) acc += __shfl_xor(acc, off);
        float es = __expf(acc);                          // |score| <= ~11: safe
        den += es;
        h8 ev = *(const h8*)(eb + ((size_t)i << 9));
        #pragma unroll
        for (int e = 0; e < 8; ++e) c8[e] += es * (float)ev[e];
      }
      #pragma unroll
      for (int e = 0; e < 8; ++e) cpart[w][e][lane] = c8[e];   // conflict-free
      if (lane == 0) dWL[w] = den;
    }
    __syncthreads();
    if (tid < 256) {
      int h0 = 2 * tid, h1 = 2 * tid + 1;
      float v0 = 0.f, v1 = 0.f;
      #pragma unroll
      for (int ww = 0; ww < 16; ++ww) {
        v0 += cpart[ww][h0 & 7][h0 >> 3];
        v1 += cpart[ww][h1 & 7][h1 >> 3];
      }
      xstu(p.CQ + (size_t)((ab << 2) | asq) * 256 + tid,
           packh2(v0 * 1.220703125e-4f, v1 * 1.220703125e-4f));   // x 2^-13
    } else if (tid == 256) {
      float d = 0.f;
      #pragma unroll
      for (int i = 0; i < 16; ++i) d += dWL[i];
      xstf(p.DEN + (ab << 2) + asq, d);
    }
    gridbar(p.flags, p.gen, ++ep);

    // ================= B: gates + h update (4 batches x 32-h slice) =================
    if (tid < 4) {
      float s = 0.f;
      #pragma unroll
      for (int sq = 0; sq < 4; ++sq) s += aldf(p.DEN + ((bg * 4 + tid) << 2) + sq);
      invL[tid] = 8192.f * __builtin_amdgcn_rcpf(s);     // 2^13 / den
    }
    __syncthreads();
    {
      int b4 = tid >> 8, pp = tid & 255;
      float lo = 0.f, hi = 0.f;
      #pragma unroll
      for (int sq = 0; sq < 4; ++sq) {
        h2 v = unpackh2(aldu(p.CQ + (size_t)(((bg * 4 + b4) << 2) | sq) * 256 + pp));
        lo += (float)v[0]; hi += (float)v[1];
      }
      float inv = invL[b4];
      ch2L[b4][pp] = h2{(f16)(lo * inv), (f16)(hi * inv)};
    }
    #pragma unroll
    for (int rep = 0; rep < 2; ++rep) {
      int idx = rep * NT + tid;
      int b4 = idx >> 9, i = idx & 511;
      float v = aldf(HNc + (size_t)(bg * 4 + b4) * 512 + i);
      float vp = __shfl_xor(v, 1);
      if (!(i & 1)) hh2L[b4][i >> 1] = h2{(f16)v, (f16)vp};
      int d = i - hsb;
      if (d >= 0 && d < 32) hfL[b4][d] = v;
    }
    if (tid < 256) {
      int b4 = tid >> 6, n2 = (tid & 63) * 2;
      float x0 = aldf(p.XF + (bg * 4 + b4) * 128 + n2);
      float x1 = aldf(p.XF + (bg * 4 + b4) * 128 + n2 + 1);
      xh2L[b4][n2 >> 1] = h2{(f16)x0, (f16)x1};
    }
    __syncthreads();
    if (tid < 384) {
      int b4 = tid & 3, g = (tid >> 2) % 3, r = tid / 12;
      int j = g * 512 + hsb + r;
      const f16* wc = p.WC + (size_t)j * 512;
      const f16* wh = p.WHH + (size_t)j * 512;
      const f16* wx = p.WX + (size_t)j * 128;
      float gc = 0.f, gh = 0.f, gx = 0.f;
      #pragma unroll 4
      for (int k4 = 0; k4 < 64; ++k4) {
        h8 cv = *(const h8*)&ch2L[b4][k4 * 4];
        h8 hv = *(const h8*)&hh2L[b4][k4 * 4];
        h8 wcv = *(const h8*)(wc + k4 * 8);
        h8 whv = *(const h8*)(wh + k4 * 8);
        const h2 *cq = (const h2*)&cv, *hq = (const h2*)&hv;
        const h2 *wcq = (const h2*)&wcv, *whq = (const h2*)&whv;
        #pragma unroll
        for (int e = 0; e < 4; ++e) {
          gc = fdot2(cq[e], wcq[e], gc);
          gh = fdot2(hq[e], whq[e], gh);
        }
      }
      #pragma unroll
      for (int k4 = 0; k4 < 16; ++k4) {
        h8 xv = *(const h8*)&xh2L[b4][k4 * 4];
        h8 wxv = *(const h8*)(wx + k4 * 8);
        const h2 *xq = (const h2*)&xv, *wxq = (const h2*)&wxv;
        #pragma unroll
        for (int e = 0; e < 4; ++e) gx = fdot2(xq[e], wxq[e], gx);
      }
      g1L[tid] = gc + gx + p.bih[j];
      g2L[tid] = gh + p.bhh[j];
    }
    __syncthreads();
    if (tid < 128) {
      int b4 = tid & 3, r = tid >> 2;
      int i0 = r * 12 + b4;
      float rr = __builtin_amdgcn_rcpf(1.f + __expf(-(g1L[i0] + g2L[i0])));
      float zz = __builtin_amdgcn_rcpf(1.f + __expf(-(g1L[i0 + 4] + g2L[i0 + 4])));
      float narg = g1L[i0 + 8] + rr * g2L[i0 + 8];
      float nn = 1.f - 2.f * __builtin_amdgcn_rcpf(1.f + __expf(2.f * narg));
      float hn = (1.f - zz) * nn + zz * hfL[b4][r];
      xstf(HNn + (size_t)(bg * 4 + b4) * 512 + hsb + r, hn);
    }
    gridbar(p.flags, p.gen, ++ep);

    // ================= C: hp, out, x from h_new =================
    #pragma unroll
    for (int rep = 0; rep < 2; ++rep) {
      int idx = rep * NT + tid;
      int b4 = idx >> 9, i = idx & 511;
      float v = aldf(HNn + (size_t)(bg * 4 + b4) * 512 + i);
      float vp = __shfl_xor(v, 1);
      if (!(i & 1)) hh2L[b4][i >> 1] = h2{(f16)v, (f16)vp};
    }
    __syncthreads();
    if (tid < 160) {
      int row = rs * 40 + (tid >> 2), b4 = tid & 3;
      const f16* wr = (row < 512) ? p.WA1 + (size_t)row * 512
                                  : p.WOUT + (size_t)(row - 512) * 512;
      float acc = 0.f;
      #pragma unroll 8
      for (int k4 = 0; k4 < 64; ++k4) {
        h8 hv = *(const h8*)&hh2L[b4][k4 * 4];
        h8 wv = *(const h8*)(wr + k4 * 8);
        const h2 *hq = (const h2*)&hv, *wq = (const h2*)&wv;
        #pragma unroll
        for (int e = 0; e < 4; ++e) acc = fdot2(hq[e], wq[e], acc);
      }
      int b = bg * 4 + b4;
      if (row < 512) {
        xstf(p.HP + (size_t)b * 512 + row, 2.f * acc);
      } else {
        int n = row - 512;
        float val = acc + p.bout[n];
        p.out[((size_t)b * T_ + step) * F_ + n] = val;
        xstf(p.XF + b * 128 + n, val);
      }
    }
    gridbar(p.flags, p.gen, ++ep);
  }
}

extern "C" void kernel_launch(void* const* d_in, const int* in_sizes, int n_in,
                              void* d_out, int out_size, void* d_ws, size_t ws_size,
                              hipStream_t stream) {
  const float* dec_input = (const float*)d_in[0];
  const float* hidden    = (const float*)d_in[1];
  const float* enc       = (const float*)d_in[2];
  // d_in[3] expected_outputs, d_in[4] dec_output_len (fixed 96) unused
  const float* Wa   = (const float*)d_in[5];
  const float* ba   = (const float*)d_in[6];
  const float* Wv   = (const float*)d_in[7];
  // d_in[8] bv cancels in softmax
  const float* Wih  = (const float*)d_in[9];
  const float* bih  = (const float*)d_in[10];
  const float* Whh  = (const float*)d_in[11];
  const float* bhh  = (const float*)d_in[12];
  const float* Wout = (const float*)d_in[13];
  const float* bout = (const float*)d_in[14];

  char* ws = (char*)d_ws;
  f16* WTS  = (f16*)(ws + WTS_OFF);
  f16* ENCP = (f16*)(ws + ENCP_OFF);
  f16* ENCF = (f16*)(ws + ENCF_OFF);

  Params p;
  p.hidden = hidden; p.dec_input = dec_input; p.Wv = Wv;
  p.bih = bih; p.bhh = bhh; p.bout = bout;
  p.ENCP = ENCP; p.ENCF = ENCF;
  p.WA1 = WTS + WA1_E; p.WHH = WTS + WHH_E; p.WC = WTS + WC_E;
  p.WX = WTS + WX_E; p.WOUT = WTS + WOUT_E;
  p.HP = (float*)(ws + HP_OFF); p.XF = (float*)(ws + XF_OFF);
  p.DEN = (float*)(ws + DEN_OFF); p.HNEW = (float*)(ws + HNEW_OFF);
  p.CQ = (u32*)(ws + CQ_OFF);
  p.flags = (u32*)(ws + FLAG_OFF); p.gen = (u32*)(ws + GEN_OFF);
  p.out = (float*)d_out;

  hipMemsetAsync(ws, 0, 20480, stream);   // flags + gen
  hipLaunchKernelGGL(transcode_enc, dim3(4096), dim3(256), 0, stream, enc, ENCF);
  hipLaunchKernelGGL(pack_weights, dim3(9216), dim3(256), 0, stream,
                     Wa, Whh, Wih, Wout, WTS);
  hipLaunchKernelGGL(mfma_encproj, dim3(256, 4), dim3(256), 0, stream,
                     (const u16*)ENCF, (const u16*)(WTS + WA2_E), ba, ENCP);

  void* args[] = {&p};
  hipLaunchCooperativeKernel((void*)decoder_phases, dim3(NB), dim3(NT), args, 0,
                             stream);
}